// Round 5
// baseline (254.543 us; speedup 1.0000x reference)
//
#include <hip/hip_runtime.h>
#include <hip/hip_bf16.h>
#include <math.h>

typedef unsigned short u16;
typedef unsigned int u32;
typedef __attribute__((ext_vector_type(8))) short bf16x8;   // 8 bf16 = 4 VGPRs
typedef __attribute__((ext_vector_type(4))) float f32x4;
typedef __attribute__((ext_vector_type(16))) float f32x16;

#define MFMA16(a,b,c) __builtin_amdgcn_mfma_f32_16x16x32_bf16(a,b,c,0,0,0)
#define MFMA32(a,b,c) __builtin_amdgcn_mfma_f32_32x32x16_bf16(a,b,c,0,0,0)

__device__ __forceinline__ u16 f2b(float f){
  unsigned u = __float_as_uint(f);
  u += 0x7fffu + ((u >> 16) & 1u);      // RNE
  return (u16)(u >> 16);
}
// packed f32x2 -> bf16x2 (header lowers to v_cvt_pk_bf16_f32 where available)
__device__ __forceinline__ u32 pack2(float a, float b){
  __hip_bfloat162 h = __float22bfloat162_rn(make_float2(a, b));
  union { __hip_bfloat162 h; u32 u; } cv;
  cv.h = h;
  return cv.u;
}

// async global->LDS, 16B per lane; LDS dest = wave-uniform base + lane*16
__device__ __forceinline__ void gll16(const void* g, void* l){
  __builtin_amdgcn_global_load_lds(
      (__attribute__((address_space(1))) void*)(const_cast<void*>(g)),
      (__attribute__((address_space(3))) void*)l, 16, 0, 0);
}

// ---------------- merged conversions ----------------
__global__ __launch_bounds__(256) void conv_k(
    const float* __restrict__ x,  const float* __restrict__ wq,
    const float* __restrict__ wk, const float* __restrict__ wv,
    const float* __restrict__ wo, u16* __restrict__ xb,
    u16* __restrict__ wqkvT, u16* __restrict__ woT)
{
  const int bid = blockIdx.x;
  if (bid < 4096){
    size_t i = ((size_t)bid*256 + threadIdx.x)*8;
    float4 a = *(const float4*)(x+i);
    float4 b = *(const float4*)(x+i+4);
    uint4 u;
    u.x = pack2(a.x, a.y);
    u.y = pack2(a.z, a.w);
    u.z = pack2(b.x, b.y);
    u.w = pack2(b.z, b.w);
    *(uint4*)(xb+i) = u;
    return;
  }
  const int id = bid - 4096;            // 0..1023
  const int z = id >> 8, rem = id & 255, i = rem >> 4, j = rem & 15;
  const float* src = (z==0)?wq:(z==1)?wk:(z==2)?wv:wo;
  u16* dst = (z<3) ? (wqkvT + (size_t)z*1024*1024) : woT;
  __shared__ u16 tile[64][72];
  const int t = threadIdx.x;
  const int cr = t >> 4, cc4 = (t & 15) * 4;
#pragma unroll
  for (int rr = 0; rr < 4; rr++){
    int r = rr*16 + cr;
    float4 v = *(const float4*)(src + (size_t)(i*64 + r)*1024 + j*64 + cc4);
    tile[cc4+0][r] = f2b(v.x);
    tile[cc4+1][r] = f2b(v.y);
    tile[cc4+2][r] = f2b(v.z);
    tile[cc4+3][r] = f2b(v.w);
  }
  __syncthreads();
  const int ro = t >> 2, co = (t & 3) * 16;
  uint4 a = *(uint4*)&tile[ro][co];
  uint4 b = *(uint4*)&tile[ro][co+8];
  u16* p = dst + (size_t)(j*64 + ro)*1024 + i*64 + co;
  *(uint4*)p = a;
  *(uint4*)(p+8) = b;
}

// ---------------- 128x128 bf16 GEMM mainloop, BK=64, C = A[M][K] * B[N][K]^T ------
__device__ __forceinline__ void gemm128_bt(
    const u16* __restrict__ A, const u16* __restrict__ B, int K,
    int rowBase, int colBase, f32x4 acc[4][4])
{
  __shared__ __align__(16) u16 lA[128*64];
  __shared__ __align__(16) u16 lB[128*64];
  const int tid = threadIdx.x, lane = tid & 63, wave = tid >> 6;
  const int wr = wave >> 1, wc = wave & 1;
  const int qd = lane >> 4, c = lane & 15;

  int aOff[4], bOff[4];                 // kb=1 offset = kb0 ^ 32
#pragma unroll
  for (int mi=0;mi<4;mi++){ int row = wr*64 + mi*16 + c; aOff[mi] = row*64 + ((qd ^ (row&7))*8); }
#pragma unroll
  for (int ni=0;ni<4;ni++){ int row = wc*64 + ni*16 + c; bOff[ni] = row*64 + ((qd ^ (row&7))*8); }

  const u16* gA[4]; const u16* gB[4]; int seg[4];
#pragma unroll
  for (int cc=0;cc<4;cc++){
    int s = wave*4 + cc;
    int row = s*8 + (lane>>3);
    int gch = (lane&7) ^ (row&7);
    gA[cc] = A + (size_t)(rowBase+row)*K + gch*8;
    gB[cc] = B + (size_t)(colBase+row)*K + gch*8;
    seg[cc] = s*512;
  }
#pragma unroll
  for (int mi=0;mi<4;mi++)
#pragma unroll
    for (int ni=0;ni<4;ni++)
#pragma unroll
      for (int e=0;e<4;e++) acc[mi][ni][e]=0.f;

  for (int k0=0; k0<K; k0+=64){
#pragma unroll
    for (int cc=0;cc<4;cc++){
      gll16(gA[cc] + k0, &lA[seg[cc]]);
      gll16(gB[cc] + k0, &lB[seg[cc]]);
    }
    __syncthreads();
#pragma unroll
    for (int kb=0; kb<2; kb++){
      const int x = kb*32;
      bf16x8 af[4], bb[4];
#pragma unroll
      for (int mi=0;mi<4;mi++) af[mi] = *(const bf16x8*)(lA + (aOff[mi]^x));
#pragma unroll
      for (int ni=0;ni<4;ni++) bb[ni] = *(const bf16x8*)(lB + (bOff[ni]^x));
#pragma unroll
      for (int ni=0;ni<4;ni++)
#pragma unroll
        for (int mi=0;mi<4;mi++)
          acc[mi][ni] = MFMA16(af[mi], bb[ni], acc[mi][ni]);
    }
    __syncthreads();
  }
}

// ---------------- QKV GEMM + RoPE epilogue ----------------
// q pre-scaled by QSC = log2(e)/128. RoPE'd dims stored interleaved (d'=2j,2j+1);
// same permutation for q and k => dot products exact.
#define QSC (1.44269504088896f/128.0f)
__global__ __launch_bounds__(256) void gemm_qkv_k(
    const u16* __restrict__ xb, const u16* __restrict__ wqkvT,
    u16* __restrict__ q, u16* __restrict__ k, u16* __restrict__ vT)
{
  f32x4 acc[4][4];
  const int rowBase = blockIdx.x*128, colBase = blockIdx.y*128;
  gemm128_bt(xb, wqkvT, 1024, rowBase, colBase, acc);
  const int tid = threadIdx.x, lane = tid & 63, wave = tid >> 6;
  const int wr = wave >> 1, wc = wave & 1;
  const int qd = lane >> 4, c = lane & 15;
  const int nb = blockIdx.y;
  const int proj = nb >> 3, h = nb & 7;

  if (proj < 2){
    u16* dst = (proj==0) ? q : k;
    const float os = (proj==0) ? QSC : 1.0f;
    if (wc == 0){
      float ang0 = __powf(10000.0f, -(float)c      * (1.0f/32.0f));
      float ang1 = __powf(10000.0f, -(float)(c+16) * (1.0f/32.0f));
#pragma unroll
      for (int mi=0;mi<4;mi++){
#pragma unroll
        for (int r=0;r<4;r++){
          int row = rowBase + wr*64 + mi*16 + qd*4 + r;
          int b = row >> 11, t = row & 2047;
          u32* dst32 = (u32*)(dst + (((long)(b*8+h))*2048 + t)*128);
          float s0,c0,s1,c1;
          __sincosf((float)t*ang0, &s0, &c0);
          __sincosf((float)t*ang1, &s1, &c1);
          { float e = acc[mi][0][r], od = acc[mi][2][r];
            dst32[c]      = pack2((e*c0 - od*s0)*os, (e*s0 + od*c0)*os); }
          { float e = acc[mi][1][r], od = acc[mi][3][r];
            dst32[16 + c] = pack2((e*c1 - od*s1)*os, (e*s1 + od*c1)*os); }
        }
      }
    } else {
#pragma unroll
      for (int mi=0;mi<4;mi++){
#pragma unroll
        for (int r=0;r<4;r++){
          int row = rowBase + wr*64 + mi*16 + qd*4 + r;
          int b = row >> 11, t = row & 2047;
          long base = (((long)(b*8+h))*2048 + t)*128 + 64;
#pragma unroll
          for (int ni=0;ni<4;ni++)
            dst[base + ni*16 + c] = f2b(acc[mi][ni][r]*os);
        }
      }
    }
  } else {
#pragma unroll
    for (int mi=0;mi<4;mi++){
      int row0 = rowBase + wr*64 + mi*16 + qd*4;
      int b = row0 >> 11, t = row0 & 2047;
#pragma unroll
      for (int ni=0;ni<4;ni++){
        int d = wc*64 + ni*16 + c;
        long base = (((long)(b*8+h))*128 + d)*2048 + t;
        *(uint2*)(vT + base) = make_uint2(pack2(acc[mi][ni][0], acc[mi][ni][1]),
                                          pack2(acc[mi][ni][2], acc[mi][ni][3]));
      }
    }
  }
}

// ---------------- flash attention v4 ----------------
// 256 threads, q-tile 64, K-tile 64. 4 waves: (qs: 2 q-strips of 32) x (kh: 2 key-halves).
// 72 KB LDS -> 2 blocks resident per CU (staggered barrier groups overlap pipes).
// Pairing {p, 31-p}: 512 blocks x 33 iters, all co-resident, no tail.
// Fixed-max softmax: P = exp2(S) with scale folded into q; l deferred per-lane.
__global__ __launch_bounds__(256, 2) void attn_k(
    const u16* __restrict__ q, const u16* __restrict__ k,
    const u16* __restrict__ vT, u16* __restrict__ o)
{
  __shared__ __align__(16) u16 smem[36864];        // 72 KB
  u16* lK = smem;                                  // [2][64 key][128 d], swiz ^(row&15)  32 KB
  u16* lV = smem + 16384;                          // [2][128 d][64 key], swiz ^(row&7)   32 KB
  u16* lP = smem + 32768;                          // [2 qs][32 q][64 key]                 8 KB
  float* scrO = (float*)smem;                      // epilogue [8][32][32] f32 = 32 KB
  float* scrL = (float*)(smem + 32768);            // epilogue [2][64]

  const int tid = threadIdx.x, lane = tid & 63, wave = tid >> 6;
  const int h2 = lane >> 5, ln = lane & 31;
  const int qs = wave >> 1, kh = wave & 1;
  const int bh = blockIdx.x, p = blockIdx.y;

  auto loadKV = [&](int kt, int buf){
    const u16* kSrc = k + ((long)bh*2048 + kt*64)*128;
#pragma unroll
    for (int cc=0; cc<4; cc++){
      int s = wave*4+cc;
      int row = s*4 + (lane>>4);
      int gch = (lane&15) ^ (row&15);
      gll16(kSrc + row*128 + gch*8, lK + buf*8192 + s*512);
    }
    const u16* vSrc = vT + (long)bh*128*2048 + kt*64;
#pragma unroll
    for (int cc=0; cc<4; cc++){
      int s = wave*4+cc;
      int row = s*8 + (lane>>3);
      int gch = (lane&7) ^ (row&7);
      gll16(vSrc + (long)row*2048 + gch*8, lV + buf*8192 + s*512);
    }
  };

  for (int sub=0; sub<2; sub++){
    const int qt = sub ? (31 - p) : p;
    const int q0 = qt*64;
    const int qw = q0 + qs*32;          // wave's q-strip base

    bf16x8 aQ[8];
    {
      const long qrow = (long)bh*2048 + qw + ln;
#pragma unroll
      for (int ch=0; ch<8; ch++)
        aQ[ch] = *(const bf16x8*)(q + qrow*128 + ch*16 + h2*8);
    }
    f32x16 accO[4];
#pragma unroll
    for (int dt=0; dt<4; dt++)
#pragma unroll
      for (int r=0;r<16;r++) accO[dt][r] = 0.f;
    float lsum = 0.f;

    __syncthreads();                    // prior sub's LDS users done
    loadKV(0, 0);
    int cur = 0;

    for (int kt=0; kt<=qt; kt++){
      __syncthreads();                  // buf[cur] ready; buf[cur^1] readers done
      if (kt < qt) loadKV(kt+1, cur^1);

      const int key0 = kt*64 + kh*32;
      if (key0 <= qw + 31){             // not fully masked for this wave
        // S^T[key][q] 32x32: A = K-half, B = Q-strip
        f32x16 accS;
#pragma unroll
        for (int r=0;r<16;r++) accS[r] = 0.f;
        const int krow = kh*32 + ln;
#pragma unroll
        for (int ch=0; ch<8; ch++){
          bf16x8 ak = *(const bf16x8*)(lK + cur*8192 + krow*128 + (((ch*2+h2) ^ (krow&15))*8));
          accS = MFMA32(ak, aQ[ch], accS);
        }

        const bool diag = (key0 + 31 > qw);
        float pe[16];
        float ls0 = 0.f, ls1 = 0.f;
#pragma unroll
        for (int r=0;r<16;r++){
          float s = accS[r];
          if (diag){
            int keyg = key0 + (r&3) + 8*(r>>2) + 4*h2;
            if (keyg > qw + ln) s = -INFINITY;   // exp2(-inf) = 0
          }
          pe[r] = exp2f(s);
          if (r & 1) ls1 += pe[r]; else ls0 += pe[r];
        }
        lsum += ls0 + ls1;

        // P -> lP [q][key] (keys contiguous, b64 per reg-quad)
        {
          u16* lpw = lP + qs*2048 + ln*64;
#pragma unroll
          for (int g=0; g<4; g++){
            uint2 w = make_uint2(pack2(pe[4*g], pe[4*g+1]), pack2(pe[4*g+2], pe[4*g+3]));
            *(uint2*)(lpw + (((kh*4+g) ^ (ln&7))*8) + h2*4) = w;
          }
        }

        // O[q][d] partial: A = P (own strip, own key-half), B = V^T
#pragma unroll
        for (int kk=0; kk<2; kk++){
          bf16x8 ap = *(const bf16x8*)(lP + qs*2048 + ln*64 + (((kh*4+kk*2+h2) ^ (ln&7))*8));
#pragma unroll
          for (int dt=0; dt<4; dt++){
            int vrow = dt*32 + ln;
            bf16x8 bv = *(const bf16x8*)(lV + cur*8192 + vrow*64 + (((kh*4+kk*2+h2) ^ (vrow&7))*8));
            accO[dt] = MFMA32(ap, bv, accO[dt]);
          }
        }
      }
      cur ^= 1;
    }

    // ---- epilogue: combine kh halves, normalize, store ----
    lsum += __shfl_xor(lsum, 32);       // fold h2 halves
    __syncthreads();                    // main-loop LDS reads done before alias reuse
    if (kh == 1){
#pragma unroll
      for (int dt=0; dt<4; dt++)
#pragma unroll
        for (int r=0;r<16;r++){
          int row = (r&3) + 8*(r>>2) + 4*h2;
          scrO[((qs*4+dt)*32 + row)*32 + ln] = accO[dt][r];
        }
      if (h2 == 0) scrL[64 + qs*32 + ln] = lsum;
    } else {
      if (h2 == 0) scrL[qs*32 + ln] = lsum;
    }
    __syncthreads();
    if (kh == 0){
      float linv[16];
#pragma unroll
      for (int r=0;r<16;r++){
        int row = (r&3) + 8*(r>>2) + 4*h2;
        linv[r] = 1.0f / (scrL[qs*32 + row] + scrL[64 + qs*32 + row]);
      }
      const int b = bh >> 3, h = bh & 7;
#pragma unroll
      for (int dt=0; dt<4; dt++){
#pragma unroll
        for (int r=0;r<16;r++){
          int row = (r&3) + 8*(r>>2) + 4*h2;
          float val = accO[dt][r] + scrO[((qs*4+dt)*32 + row)*32 + ln];
          int t = q0 + qs*32 + row;
          o[((long)(b*2048 + t))*1024 + h*128 + dt*32 + ln] = f2b(val * linv[r]);
        }
      }
    }
  }
}

// ---------------- output projection ----------------
__global__ __launch_bounds__(256) void gemm_out_k(
    const u16* __restrict__ oa, const u16* __restrict__ woT, float* __restrict__ out)
{
  f32x4 acc[4][4];
  const int rowBase = blockIdx.x*128, colBase = blockIdx.y*128;
  gemm128_bt(oa, woT, 1024, rowBase, colBase, acc);
  const int lane = threadIdx.x & 63, wave = threadIdx.x >> 6;
  const int wr = wave >> 1, wc = wave & 1;
  const int qd = lane >> 4, c = lane & 15;
#pragma unroll
  for (int mi=0;mi<4;mi++){
#pragma unroll
    for (int ni=0;ni<4;ni++){
      int row = rowBase + wr*64 + mi*16 + qd*4;
      int col = colBase + wc*64 + ni*16 + c;
#pragma unroll
      for (int r=0;r<4;r++)
        out[(size_t)(row+r)*1024 + col] = acc[mi][ni][r];
    }
  }
}

extern "C" void kernel_launch(void* const* d_in, const int* in_sizes, int n_in,
                              void* d_out, int out_size, void* d_ws, size_t ws_size,
                              hipStream_t stream) {
  const float* x  = (const float*)d_in[0];
  const float* wq = (const float*)d_in[1];
  const float* wk = (const float*)d_in[2];
  const float* wv = (const float*)d_in[3];
  const float* wo = (const float*)d_in[4];
  float* out = (float*)d_out;

  char* ws = (char*)d_ws;
  u16* xb    = (u16*)(ws);
  u16* wqkvT = (u16*)(ws + (16u<<20));
  u16* woT   = (u16*)(ws + (22u<<20));
  u16* qb    = (u16*)(ws + (24u<<20));
  u16* kb    = (u16*)(ws + (40u<<20));
  u16* vT    = (u16*)(ws + (56u<<20));
  u16* ob    = xb;   // reuse xb after gemm_qkv

  conv_k    <<<dim3(5120), dim3(256), 0, stream>>>(x, wq, wk, wv, wo, xb, wqkvT, woT);
  gemm_qkv_k<<<dim3(64,24), dim3(256), 0, stream>>>(xb, wqkvT, qb, kb, vT);
  attn_k    <<<dim3(32,16), dim3(256), 0, stream>>>(qb, kb, vT, ob);
  gemm_out_k<<<dim3(64,8),  dim3(256), 0, stream>>>(ob, woT, out);
}